// Round 1
// baseline (120.837 us; speedup 1.0000x reference)
//
#include <hip/hip_runtime.h>
#include <hip/hip_bf16.h>
#include <math.h>

typedef short bf16x8 __attribute__((ext_vector_type(8)));
typedef float f32x4 __attribute__((ext_vector_type(4)));
typedef unsigned int u32;
typedef unsigned short u16;

constexpr int Bb = 8, LQn = 1024, LKn = 1024, En = 512, Hn = 8, Dn = 64;
constexpr int Mtok = Bb * LQn;  // 8192
constexpr float SCALE = 0.04419417382415922f;  // 1/sqrt(512)

__device__ __forceinline__ u16 f2bf(float f) {
  u32 u = __builtin_bit_cast(u32, f);
  u32 r = (u + 0x7fffu + ((u >> 16) & 1u)) >> 16;
  return (u16)r;
}
__device__ __forceinline__ float bf2f(u16 h) {
  u32 u = ((u32)h) << 16;
  return __builtin_bit_cast(float, u);
}

// async 16B global -> LDS copy (wave-uniform LDS base + lane*16 required)
__device__ __forceinline__ void async_lds16(const void* gsrc, void* ldst) {
  __builtin_amdgcn_global_load_lds(
      (const __attribute__((address_space(1))) u32*)gsrc,
      (__attribute__((address_space(3))) u32*)ldst, 16, 0, 0);
}

// ---------------- fp32 -> bf16 conversion (vectorized) ----------------
__global__ void cvt_bf16_kernel(const float* __restrict__ in, u16* __restrict__ out, int n4) {
  int i = blockIdx.x * blockDim.x + threadIdx.x;
  if (i >= n4) return;
  float4 v = reinterpret_cast<const float4*>(in)[i];
  ushort4 o;
  o.x = f2bf(v.x); o.y = f2bf(v.y); o.z = f2bf(v.z); o.w = f2bf(v.w);
  reinterpret_cast<ushort4*>(out)[i] = o;
}

// ---------------- sin(|row-sum|) masks, double accumulation ----------------
__global__ void mask_kernel(const float* __restrict__ x, float* __restrict__ mask) {
  int row = blockIdx.x * 4 + (threadIdx.x >> 6);
  int lane = threadIdx.x & 63;
  const float* p = x + (size_t)row * En;
  double s = 0.0;
#pragma unroll
  for (int j = 0; j < En / 64; ++j) s += (double)p[lane + j * 64];
#pragma unroll
  for (int off = 32; off > 0; off >>= 1) s += __shfl_down(s, off, 64);
  if (lane == 0) mask[row] = (float)sin(fabs(s));
}

// ---------------- GEMM: C[M][N] = relu(A[M][K] * Bm[N][K]^T + bias), bf16 out ----
// BIAS_ROW=0: bias indexed by output col; BIAS_ROW=1: by output row.
template <int BIAS_ROW>
__global__ __launch_bounds__(256, 2) void gemm_bt_relu(
    const u16* __restrict__ A, const u16* __restrict__ Bm,
    const float* __restrict__ bias, u16* __restrict__ C,
    int M, int N, int ldc) {
  constexpr int K = 512, BM = 128, BN = 64, BK = 64;
  __shared__ u16 sA[BM * BK];
  __shared__ u16 sB[BN * BK];
  int tid = threadIdx.x;
  int lane = tid & 63;
  int w = tid >> 6;
  int row0 = blockIdx.y * BM;
  int col0 = blockIdx.x * BN;
  int wm = w >> 1, wn = w & 1;
  int rgrp = lane >> 4, cidx = lane & 15;

  f32x4 acc[4][2];
#pragma unroll
  for (int mi = 0; mi < 4; ++mi)
#pragma unroll
    for (int ni = 0; ni < 2; ++ni) acc[mi][ni] = f32x4{0.f, 0.f, 0.f, 0.f};

  for (int kt = 0; kt < K / BK; ++kt) {
    int k0 = kt * BK;
    __syncthreads();
#pragma unroll
    for (int rr = 0; rr < 4; ++rr) {  // A tile: 128x64 bf16 = 1024 16B chunks
      int cid = rr * 256 + tid;
      int r = cid >> 3, c = cid & 7;
      async_lds16(A + (size_t)(row0 + r) * K + k0 + c * 8, &sA[cid * 8]);
    }
#pragma unroll
    for (int rr = 0; rr < 2; ++rr) {  // B tile: 64x64 bf16 = 512 chunks
      int cid = rr * 256 + tid;
      int r = cid >> 3, c = cid & 7;
      async_lds16(Bm + (size_t)(col0 + r) * K + k0 + c * 8, &sB[cid * 8]);
    }
    __syncthreads();
#pragma unroll
    for (int kk = 0; kk < 2; ++kk) {
      bf16x8 a[4], b[2];
#pragma unroll
      for (int mi = 0; mi < 4; ++mi)
        a[mi] = *reinterpret_cast<const bf16x8*>(
            &sA[(wm * 64 + mi * 16 + cidx) * BK + kk * 32 + rgrp * 8]);
#pragma unroll
      for (int ni = 0; ni < 2; ++ni)
        b[ni] = *reinterpret_cast<const bf16x8*>(
            &sB[(wn * 32 + ni * 16 + cidx) * BK + kk * 32 + rgrp * 8]);
#pragma unroll
      for (int mi = 0; mi < 4; ++mi)
#pragma unroll
        for (int ni = 0; ni < 2; ++ni)
          acc[mi][ni] = __builtin_amdgcn_mfma_f32_16x16x32_bf16(a[mi], b[ni], acc[mi][ni], 0, 0, 0);
    }
  }
  // epilogue: bias + relu + bf16 store. C/D layout: col=lane&15, row=(lane>>4)*4+r
#pragma unroll
  for (int mi = 0; mi < 4; ++mi)
#pragma unroll
    for (int ni = 0; ni < 2; ++ni)
#pragma unroll
      for (int r = 0; r < 4; ++r) {
        int grow = row0 + wm * 64 + mi * 16 + rgrp * 4 + r;
        int gcol = col0 + wn * 32 + ni * 16 + cidx;
        float v = acc[mi][ni][r] + (BIAS_ROW ? bias[grow] : bias[gcol]);
        v = v > 0.f ? v : 0.f;
        C[(size_t)grow * ldc + gcol] = f2bf(v);
      }
}

// ---------------- fused masked attention ----------------
// grid: (LQ/64, B*H). block: 256 (4 waves, 16 q-rows each).
// No max-subtraction needed: q,k >= 0 (ReLU) => scores in [0, ~1]; masked keys
// contribute exp(NEG)==0 exactly, matching the reference bit-behavior.
__global__ __launch_bounds__(256, 2) void attn_kernel(
    const u16* __restrict__ qb, const u16* __restrict__ kb, const u16* __restrict__ vtb,
    const float* __restrict__ kmask, const float* __restrict__ qmask,
    float* __restrict__ out) {
  __shared__ u16 sQ[64 * 64];
  __shared__ u16 sK[64 * 64];
  __shared__ u16 sV[64 * 64];  // V^T tile: rows=d (64), cols=k (64)
  __shared__ u16 sP[64 * 64];  // wave-private 16x64 slices
  int tid = threadIdx.x, lane = tid & 63, w = tid >> 6;
  int qblk = blockIdx.x;
  int b = blockIdx.y >> 3, h = blockIdx.y & 7;
  int rgrp = lane >> 4, cidx = lane & 15;

  const u16* qbase = qb + ((size_t)(b * LQn) + qblk * 64) * En + h * Dn;
#pragma unroll
  for (int rr = 0; rr < 2; ++rr) {  // Q tile 64x64
    int cid = rr * 256 + tid;
    int r = cid >> 3, c = cid & 7;
    async_lds16(qbase + (size_t)r * En + c * 8, &sQ[cid * 8]);
  }
  __syncthreads();
  bf16x8 qa[2];
  qa[0] = *reinterpret_cast<const bf16x8*>(&sQ[(w * 16 + cidx) * 64 + rgrp * 8]);
  qa[1] = *reinterpret_cast<const bf16x8*>(&sQ[(w * 16 + cidx) * 64 + 32 + rgrp * 8]);

  f32x4 acc_o[4];
#pragma unroll
  for (int dt = 0; dt < 4; ++dt) acc_o[dt] = f32x4{0.f, 0.f, 0.f, 0.f};
  float den[4] = {0.f, 0.f, 0.f, 0.f};

  const u16* kbase = kb + (size_t)(b * LKn) * En + h * Dn;
  const u16* vbase = vtb + (size_t)(h * Dn) * Mtok + b * LKn;
  const float* kmb = kmask + b * LKn;

  for (int kt = 0; kt < LKn / 64; ++kt) {
    __syncthreads();
#pragma unroll
    for (int rr = 0; rr < 2; ++rr) {
      int cid = rr * 256 + tid;
      int r = cid >> 3, c = cid & 7;
      async_lds16(kbase + (size_t)(kt * 64 + r) * En + c * 8, &sK[cid * 8]);
      async_lds16(vbase + (size_t)r * Mtok + kt * 64 + c * 8, &sV[cid * 8]);
    }
    __syncthreads();
    // S = Q K^T (per-wave 16x64), then P = mask ? 0 : exp(S*scale) -> bf16 LDS
#pragma unroll
    for (int ktile = 0; ktile < 4; ++ktile) {
      bf16x8 kf0 = *reinterpret_cast<const bf16x8*>(&sK[(ktile * 16 + cidx) * 64 + rgrp * 8]);
      bf16x8 kf1 = *reinterpret_cast<const bf16x8*>(&sK[(ktile * 16 + cidx) * 64 + 32 + rgrp * 8]);
      f32x4 s = f32x4{0.f, 0.f, 0.f, 0.f};
      s = __builtin_amdgcn_mfma_f32_16x16x32_bf16(qa[0], kf0, s, 0, 0, 0);
      s = __builtin_amdgcn_mfma_f32_16x16x32_bf16(qa[1], kf1, s, 0, 0, 0);
      float km = kmb[kt * 64 + ktile * 16 + cidx];
      bool on = km > 0.f;
#pragma unroll
      for (int r = 0; r < 4; ++r) {
        float p = on ? __expf(s[r] * SCALE) : 0.f;
        u16 pb = f2bf(p);
        den[r] += bf2f(pb);  // denominator consistent with bf16 numerator
        sP[(w * 16 + rgrp * 4 + r) * 64 + ktile * 16 + cidx] = pb;
      }
    }
    // PV: out(16q x 64d) += P(16q x 64k) * V(64k x 64d); wave-private P, no barrier
#pragma unroll
    for (int kk = 0; kk < 2; ++kk) {
      bf16x8 pa = *reinterpret_cast<const bf16x8*>(&sP[(w * 16 + cidx) * 64 + kk * 32 + rgrp * 8]);
#pragma unroll
      for (int dt = 0; dt < 4; ++dt) {
        bf16x8 vf = *reinterpret_cast<const bf16x8*>(&sV[(dt * 16 + cidx) * 64 + kk * 32 + rgrp * 8]);
        acc_o[dt] = __builtin_amdgcn_mfma_f32_16x16x32_bf16(pa, vf, acc_o[dt], 0, 0, 0);
      }
    }
  }
  // reduce denominators across the 16 lanes sharing the same rows
#pragma unroll
  for (int r = 0; r < 4; ++r)
#pragma unroll
    for (int off = 8; off > 0; off >>= 1) den[r] += __shfl_xor(den[r], off, 64);

  const float* qmb = qmask + (size_t)b * LQn + qblk * 64 + w * 16;
  const u16* qres = qbase + (size_t)(w * 16) * En;
  float* obase = out + ((size_t)(b * LQn) + qblk * 64 + w * 16) * En + h * Dn;
#pragma unroll
  for (int r = 0; r < 4; ++r) {
    int qr = rgrp * 4 + r;
    float fac = qmb[qr] / den[r];
#pragma unroll
    for (int dt = 0; dt < 4; ++dt) {
      float v = acc_o[dt][r] * fac + bf2f(qres[(size_t)qr * En + dt * 16 + cidx]);
      obase[(size_t)qr * En + dt * 16 + cidx] = v;
    }
  }
}

extern "C" void kernel_launch(void* const* d_in, const int* in_sizes, int n_in,
                              void* d_out, int out_size, void* d_ws, size_t ws_size,
                              hipStream_t stream) {
  const float* x1 = (const float*)d_in[0];
  const float* x2 = (const float*)d_in[1];
  const float* Wq = (const float*)d_in[2];
  const float* bq = (const float*)d_in[3];
  const float* Wk = (const float*)d_in[4];
  const float* bk = (const float*)d_in[5];
  const float* Wv = (const float*)d_in[6];
  const float* bv = (const float*)d_in[7];
  float* out = (float*)d_out;

  char* ws = (char*)d_ws;
  size_t o = 0;
  u16* x1b = (u16*)(ws + o); o += (size_t)Mtok * En * 2;
  u16* x2b = (u16*)(ws + o); o += (size_t)Mtok * En * 2;
  u16* wqb = (u16*)(ws + o); o += (size_t)En * En * 2;
  u16* wkb = (u16*)(ws + o); o += (size_t)En * En * 2;
  u16* wvb = (u16*)(ws + o); o += (size_t)En * En * 2;
  u16* qbq = (u16*)(ws + o); o += (size_t)Mtok * En * 2;
  u16* kbk = (u16*)(ws + o); o += (size_t)Mtok * En * 2;
  u16* vtb = (u16*)(ws + o); o += (size_t)Mtok * En * 2;  // [E][Mtok] transposed
  float* kmask = (float*)(ws + o); o += (size_t)Mtok * 4;
  float* qmask = (float*)(ws + o); o += (size_t)Mtok * 4;

  int n4x = Mtok * En / 4;  // 1048576
  int n4w = En * En / 4;    // 65536
  cvt_bf16_kernel<<<n4x / 256, 256, 0, stream>>>(x1, x1b, n4x);
  cvt_bf16_kernel<<<n4x / 256, 256, 0, stream>>>(x2, x2b, n4x);
  cvt_bf16_kernel<<<n4w / 256, 256, 0, stream>>>(Wq, wqb, n4w);
  cvt_bf16_kernel<<<n4w / 256, 256, 0, stream>>>(Wk, wkb, n4w);
  cvt_bf16_kernel<<<n4w / 256, 256, 0, stream>>>(Wv, wvb, n4w);

  mask_kernel<<<Mtok / 4, 256, 0, stream>>>(x1, qmask);
  mask_kernel<<<Mtok / 4, 256, 0, stream>>>(x2, kmask);

  dim3 gq(En / 64, Mtok / 128);  // (8, 64)
  gemm_bt_relu<0><<<gq, 256, 0, stream>>>(x1b, wqb, bq, qbq, Mtok, En, En);
  gemm_bt_relu<0><<<gq, 256, 0, stream>>>(x2b, wkb, bk, kbk, Mtok, En, En);
  dim3 gv(Mtok / 64, En / 128);  // (128, 4) -> vt[f][t] = relu(Wv . x2^T), bias per row
  gemm_bt_relu<1><<<gv, 256, 0, stream>>>(wvb, x2b, bv, vtb, En, Mtok, Mtok);

  dim3 ga(LQn / 64, Bb * Hn);  // (16, 64)
  attn_kernel<<<ga, 256, 0, stream>>>(qbq, kbk, vtb, kmask, qmask, out);
}

// Round 2
// 91.390 us; speedup vs baseline: 1.3222x; 1.3222x over previous
//
#include <hip/hip_runtime.h>
#include <hip/hip_bf16.h>
#include <math.h>

typedef short bf16x8 __attribute__((ext_vector_type(8)));
typedef float f32x4 __attribute__((ext_vector_type(4)));
typedef unsigned int u32;
typedef unsigned short u16;

constexpr int Bb = 8, LQn = 1024, LKn = 1024, En = 512, Hn = 8, Dn = 64;
constexpr int Mtok = Bb * LQn;  // 8192
constexpr float SCALE = 0.04419417382415922f;  // 1/sqrt(512)

__device__ __forceinline__ u16 f2bf(float f) {
  u32 u = __builtin_bit_cast(u32, f);
  u32 r = (u + 0x7fffu + ((u >> 16) & 1u)) >> 16;
  return (u16)r;
}
__device__ __forceinline__ float bf2f(u16 h) {
  u32 u = ((u32)h) << 16;
  return __builtin_bit_cast(float, u);
}

// async 16B global -> LDS copy (wave-uniform LDS base + lane*16 required)
__device__ __forceinline__ void async_lds16(const void* gsrc, void* ldst) {
  __builtin_amdgcn_global_load_lds(
      (const __attribute__((address_space(1))) u32*)gsrc,
      (__attribute__((address_space(3))) u32*)ldst, 16, 0, 0);
}

// ---------------- fused fp32->bf16 + sin(|row-sum|) mask ----------------
// one 64-lane wave per 512-elem row; 4 rows per block
__global__ void cvtmask_kernel(const float* __restrict__ x, u16* __restrict__ xb,
                               float* __restrict__ mask) {
  int row = blockIdx.x * 4 + (threadIdx.x >> 6);
  int lane = threadIdx.x & 63;
  const float4* p = reinterpret_cast<const float4*>(x + (size_t)row * En);
  ushort4* ob = reinterpret_cast<ushort4*>(xb + (size_t)row * En);
  double s = 0.0;
#pragma unroll
  for (int j = 0; j < En / 256; ++j) {
    float4 v = p[lane + j * 64];
    s += (double)v.x + (double)v.y + (double)v.z + (double)v.w;
    ushort4 o;
    o.x = f2bf(v.x); o.y = f2bf(v.y); o.z = f2bf(v.z); o.w = f2bf(v.w);
    ob[lane + j * 64] = o;
  }
#pragma unroll
  for (int off = 32; off > 0; off >>= 1) s += __shfl_down(s, off, 64);
  if (lane == 0) mask[row] = (float)sin(fabs(s));
}

// ---------------- 3 weight matrices fp32 -> bf16 in one launch ----------------
__global__ void cvt3_kernel(const float* __restrict__ a, const float* __restrict__ b,
                            const float* __restrict__ c, u16* __restrict__ oa,
                            u16* __restrict__ ob, u16* __restrict__ oc, int n4) {
  int i = blockIdx.x * blockDim.x + threadIdx.x;
  const float* src;
  u16* dst;
  int j = i;
  if (j < n4) { src = a; dst = oa; }
  else if (j < 2 * n4) { src = b; dst = ob; j -= n4; }
  else { src = c; dst = oc; j -= 2 * n4; }
  float4 v = reinterpret_cast<const float4*>(src)[j];
  ushort4 o;
  o.x = f2bf(v.x); o.y = f2bf(v.y); o.z = f2bf(v.z); o.w = f2bf(v.w);
  reinterpret_cast<ushort4*>(dst)[j] = o;
}

// ---------------- GEMM: C[M][N] = relu(A[M][K] * Bm[N][K]^T + bias), bf16 out ----
// LDS tiles XOR-swizzled on 16B chunks (chunk' = chunk ^ (row&7)) via
// pre-swizzled global source (global_load_lds writes linearly; rule #21).
template <int BIAS_ROW>
__global__ __launch_bounds__(256, 2) void gemm_bt_relu(
    const u16* __restrict__ A, const u16* __restrict__ Bm,
    const float* __restrict__ bias, u16* __restrict__ C,
    int M, int N, int ldc) {
  constexpr int K = 512, BM = 128, BN = 64, BK = 64;
  __shared__ u16 sA[BM * BK];
  __shared__ u16 sB[BN * BK];
  int tid = threadIdx.x;
  int lane = tid & 63;
  int w = tid >> 6;
  int row0 = blockIdx.y * BM;
  int col0 = blockIdx.x * BN;
  int wm = w >> 1, wn = w & 1;
  int rgrp = lane >> 4, cidx = lane & 15;

  f32x4 acc[4][2];
#pragma unroll
  for (int mi = 0; mi < 4; ++mi)
#pragma unroll
    for (int ni = 0; ni < 2; ++ni) acc[mi][ni] = f32x4{0.f, 0.f, 0.f, 0.f};

  for (int kt = 0; kt < K / BK; ++kt) {
    int k0 = kt * BK;
    __syncthreads();
#pragma unroll
    for (int rr = 0; rr < 4; ++rr) {  // A tile: 128x64 bf16 = 1024 16B chunks
      int cid = rr * 256 + tid;
      int r = cid >> 3, c = cid & 7;
      int cg = c ^ (r & 7);
      async_lds16(A + (size_t)(row0 + r) * K + k0 + cg * 8, &sA[cid * 8]);
    }
#pragma unroll
    for (int rr = 0; rr < 2; ++rr) {  // B tile: 64x64 bf16 = 512 chunks
      int cid = rr * 256 + tid;
      int r = cid >> 3, c = cid & 7;
      int cg = c ^ (r & 7);
      async_lds16(Bm + (size_t)(col0 + r) * K + k0 + cg * 8, &sB[cid * 8]);
    }
    __syncthreads();
#pragma unroll
    for (int kk = 0; kk < 2; ++kk) {
      bf16x8 a[4], b[2];
#pragma unroll
      for (int mi = 0; mi < 4; ++mi) {
        int row = wm * 64 + mi * 16 + cidx;
        a[mi] = *reinterpret_cast<const bf16x8*>(
            &sA[row * BK + ((kk * 4 + rgrp) ^ (row & 7)) * 8]);
      }
#pragma unroll
      for (int ni = 0; ni < 2; ++ni) {
        int row = wn * 32 + ni * 16 + cidx;
        b[ni] = *reinterpret_cast<const bf16x8*>(
            &sB[row * BK + ((kk * 4 + rgrp) ^ (row & 7)) * 8]);
      }
#pragma unroll
      for (int mi = 0; mi < 4; ++mi)
#pragma unroll
        for (int ni = 0; ni < 2; ++ni)
          acc[mi][ni] = __builtin_amdgcn_mfma_f32_16x16x32_bf16(a[mi], b[ni], acc[mi][ni], 0, 0, 0);
    }
  }
  // epilogue: bias + relu + bf16 store. C/D layout: col=lane&15, row=(lane>>4)*4+r
#pragma unroll
  for (int mi = 0; mi < 4; ++mi)
#pragma unroll
    for (int ni = 0; ni < 2; ++ni)
#pragma unroll
      for (int r = 0; r < 4; ++r) {
        int grow = row0 + wm * 64 + mi * 16 + rgrp * 4 + r;
        int gcol = col0 + wn * 32 + ni * 16 + cidx;
        float v = acc[mi][ni][r] + (BIAS_ROW ? bias[grow] : bias[gcol]);
        v = v > 0.f ? v : 0.f;
        C[(size_t)grow * ldc + gcol] = f2bf(v);
      }
}

// ---------------- fused masked attention ----------------
// grid: (LQ/64, B*H). block: 256 (4 waves, 16 q-rows each).
// q,k >= 0 (ReLU) => scores in [0,~1]: no max tracking; masked keys give exact 0.
// All LDS tiles XOR-swizzled (16B-chunk granularity) to kill the 16-way
// bank conflicts of 128B-row ds_read_b128.
__global__ __launch_bounds__(256, 2) void attn_kernel(
    const u16* __restrict__ qb, const u16* __restrict__ kb, const u16* __restrict__ vtb,
    const float* __restrict__ kmask, const float* __restrict__ qmask,
    float* __restrict__ out) {
  __shared__ u16 sQ[64 * 64];
  __shared__ u16 sK[64 * 64];
  __shared__ u16 sV[64 * 64];  // V^T tile: rows=d (64), cols=k (64)
  __shared__ u16 sP[64 * 64];  // wave-private 16x64 slices
  int tid = threadIdx.x, lane = tid & 63, w = tid >> 6;
  int qblk = blockIdx.x;
  int b = blockIdx.y >> 3, h = blockIdx.y & 7;
  int rgrp = lane >> 4, cidx = lane & 15;

  const u16* qbase = qb + ((size_t)(b * LQn) + qblk * 64) * En + h * Dn;
#pragma unroll
  for (int rr = 0; rr < 2; ++rr) {  // Q tile 64x64
    int cid = rr * 256 + tid;
    int r = cid >> 3, c = cid & 7;
    int cg = c ^ (r & 7);
    async_lds16(qbase + (size_t)r * En + cg * 8, &sQ[cid * 8]);
  }
  __syncthreads();
  bf16x8 qa[2];
  {
    int row = w * 16 + cidx;
    qa[0] = *reinterpret_cast<const bf16x8*>(&sQ[row * 64 + (rgrp ^ (row & 7)) * 8]);
    qa[1] = *reinterpret_cast<const bf16x8*>(&sQ[row * 64 + ((4 + rgrp) ^ (row & 7)) * 8]);
  }

  f32x4 acc_o[4];
#pragma unroll
  for (int dt = 0; dt < 4; ++dt) acc_o[dt] = f32x4{0.f, 0.f, 0.f, 0.f};
  float den[4] = {0.f, 0.f, 0.f, 0.f};

  const u16* kbase = kb + (size_t)(b * LKn) * En + h * Dn;
  const u16* vbase = vtb + (size_t)(h * Dn) * Mtok + b * LKn;
  const float* kmb = kmask + b * LKn;

  for (int kt = 0; kt < LKn / 64; ++kt) {
    __syncthreads();
#pragma unroll
    for (int rr = 0; rr < 2; ++rr) {
      int cid = rr * 256 + tid;
      int r = cid >> 3, c = cid & 7;
      int cg = c ^ (r & 7);
      async_lds16(kbase + (size_t)(kt * 64 + r) * En + cg * 8, &sK[cid * 8]);
      async_lds16(vbase + (size_t)r * Mtok + kt * 64 + cg * 8, &sV[cid * 8]);
    }
    __syncthreads();
    // S = Q K^T (per-wave 16x64), then P = mask ? 0 : exp(S*scale) -> bf16 LDS
#pragma unroll
    for (int ktile = 0; ktile < 4; ++ktile) {
      int krow = ktile * 16 + cidx;
      bf16x8 kf0 = *reinterpret_cast<const bf16x8*>(&sK[krow * 64 + (rgrp ^ (krow & 7)) * 8]);
      bf16x8 kf1 = *reinterpret_cast<const bf16x8*>(&sK[krow * 64 + ((4 + rgrp) ^ (krow & 7)) * 8]);
      f32x4 s = f32x4{0.f, 0.f, 0.f, 0.f};
      s = __builtin_amdgcn_mfma_f32_16x16x32_bf16(qa[0], kf0, s, 0, 0, 0);
      s = __builtin_amdgcn_mfma_f32_16x16x32_bf16(qa[1], kf1, s, 0, 0, 0);
      float km = kmb[kt * 64 + ktile * 16 + cidx];
      bool on = km > 0.f;
#pragma unroll
      for (int r = 0; r < 4; ++r) {
        float p = on ? __expf(s[r] * SCALE) : 0.f;
        u16 pb = f2bf(p);
        den[r] += bf2f(pb);  // denominator consistent with bf16 numerator
        int prow = w * 16 + rgrp * 4 + r;
        sP[prow * 64 + ((ktile * 16 + cidx) ^ ((prow & 7) << 3))] = pb;
      }
    }
    // PV: out(16q x 64d) += P(16q x 64k) * V(64k x 64d); wave-private P, no barrier
#pragma unroll
    for (int kk = 0; kk < 2; ++kk) {
      int prow = w * 16 + cidx;
      bf16x8 pa = *reinterpret_cast<const bf16x8*>(
          &sP[prow * 64 + ((kk * 4 + rgrp) ^ (prow & 7)) * 8]);
#pragma unroll
      for (int dt = 0; dt < 4; ++dt) {
        int vrow = dt * 16 + cidx;
        bf16x8 vf = *reinterpret_cast<const bf16x8*>(
            &sV[vrow * 64 + ((kk * 4 + rgrp) ^ (vrow & 7)) * 8]);
        acc_o[dt] = __builtin_amdgcn_mfma_f32_16x16x32_bf16(pa, vf, acc_o[dt], 0, 0, 0);
      }
    }
  }
  // reduce denominators across the 16 lanes sharing the same rows
#pragma unroll
  for (int r = 0; r < 4; ++r)
#pragma unroll
    for (int off = 8; off > 0; off >>= 1) den[r] += __shfl_xor(den[r], off, 64);

  const float* qmb = qmask + (size_t)b * LQn + qblk * 64 + w * 16;
  const u16* qres = qbase + (size_t)(w * 16) * En;
  float* obase = out + ((size_t)(b * LQn) + qblk * 64 + w * 16) * En + h * Dn;
#pragma unroll
  for (int r = 0; r < 4; ++r) {
    int qr = rgrp * 4 + r;
    float fac = qmb[qr] / den[r];
#pragma unroll
    for (int dt = 0; dt < 4; ++dt) {
      float v = acc_o[dt][r] * fac + bf2f(qres[(size_t)qr * En + dt * 16 + cidx]);
      obase[(size_t)qr * En + dt * 16 + cidx] = v;
    }
  }
}

extern "C" void kernel_launch(void* const* d_in, const int* in_sizes, int n_in,
                              void* d_out, int out_size, void* d_ws, size_t ws_size,
                              hipStream_t stream) {
  const float* x1 = (const float*)d_in[0];
  const float* x2 = (const float*)d_in[1];
  const float* Wq = (const float*)d_in[2];
  const float* bq = (const float*)d_in[3];
  const float* Wk = (const float*)d_in[4];
  const float* bk = (const float*)d_in[5];
  const float* Wv = (const float*)d_in[6];
  const float* bv = (const float*)d_in[7];
  float* out = (float*)d_out;

  char* ws = (char*)d_ws;
  size_t o = 0;
  u16* x1b = (u16*)(ws + o); o += (size_t)Mtok * En * 2;
  u16* x2b = (u16*)(ws + o); o += (size_t)Mtok * En * 2;
  u16* wqb = (u16*)(ws + o); o += (size_t)En * En * 2;
  u16* wkb = (u16*)(ws + o); o += (size_t)En * En * 2;
  u16* wvb = (u16*)(ws + o); o += (size_t)En * En * 2;
  u16* qbq = (u16*)(ws + o); o += (size_t)Mtok * En * 2;
  u16* kbk = (u16*)(ws + o); o += (size_t)Mtok * En * 2;
  u16* vtb = (u16*)(ws + o); o += (size_t)Mtok * En * 2;  // [E][Mtok] transposed
  float* kmask = (float*)(ws + o); o += (size_t)Mtok * 4;
  float* qmask = (float*)(ws + o); o += (size_t)Mtok * 4;

  cvtmask_kernel<<<Mtok / 4, 256, 0, stream>>>(x1, x1b, qmask);
  cvtmask_kernel<<<Mtok / 4, 256, 0, stream>>>(x2, x2b, kmask);

  int n4w = En * En / 4;  // 65536
  cvt3_kernel<<<3 * n4w / 256, 256, 0, stream>>>(Wq, Wk, Wv, wqb, wkb, wvb, n4w);

  dim3 gq(En / 64, Mtok / 128);  // (8, 64)
  gemm_bt_relu<0><<<gq, 256, 0, stream>>>(x1b, wqb, bq, qbq, Mtok, En, En);
  gemm_bt_relu<0><<<gq, 256, 0, stream>>>(x2b, wkb, bk, kbk, Mtok, En, En);
  dim3 gv(Mtok / 64, En / 128);  // (128, 4) -> vt[f][t] = relu(Wv . x2^T), bias per row
  gemm_bt_relu<1><<<gv, 256, 0, stream>>>(wvb, x2b, bv, vtb, En, Mtok, Mtok);

  dim3 ga(LQn / 64, Bb * Hn);  // (16, 64)
  attn_kernel<<<ga, 256, 0, stream>>>(qbq, kbk, vtb, kmask, qmask, out);
}